// Round 4
// baseline (370.621 us; speedup 1.0000x reference)
//
#include <hip/hip_runtime.h>
#include <math.h>

#define H 1536
#define W 2048
#define NPIX (H*W)
#define SS 2000
#define SIDE 20
#define THRC 0.2f

typedef unsigned long long u64;

// ---------------- workspace layout (bytes) ----------------
constexpr size_t OFF_BITL  = 0;                              // u64[H*32]   384 KB (region -> inlier bitmaps)
constexpr size_t OFF_BITR  = OFF_BITL + (size_t)H*32*8;      // u64[H*32]   384 KB
constexpr size_t OFF_PART  = OFF_BITR + (size_t)H*32*8;      // float[H*8]   48 KB
constexpr size_t OFF_WPFX  = OFF_PART + (size_t)H*8*4;       // u8[H*32]     48 KB (per-row word-prefix popcounts)
constexpr size_t OFF_NORM  = OFF_WPFX + (size_t)H*32;        // float4[H*64] 1.5 MB (per-flagged-pixel normals)
constexpr size_t OFF_INFO  = OFF_NORM + (size_t)H*64*16;     // float4[H]    24 KB {lx, rx, ld, rd}
constexpr size_t OFF_VALID = OFF_INFO + (size_t)H*16;        // int[H]        6 KB

// ---------------- math helpers (contract off: match numpy per-op rounding) ----
struct F3 { float x, y, z; };
struct K9 { float k[9]; };

__device__ __forceinline__ F3 camAt(const float* __restrict__ depth, const K9& Ki, int y, int x) {
#pragma clang fp contract(off)
    float d = depth[y * W + x];
    float u = (float)x, v = (float)y;
    F3 p;
    p.x = (Ki.k[0] * u + Ki.k[1] * v + Ki.k[2]) * d;
    p.y = (Ki.k[3] * u + Ki.k[4] * v + Ki.k[5]) * d;
    p.z = (Ki.k[6] * u + Ki.k[7] * v + Ki.k[8]) * d;
    return p;
}

__device__ __forceinline__ F3 f3sub(F3 a, F3 b) {
#pragma clang fp contract(off)
    F3 r; r.x = a.x - b.x; r.y = a.y - b.y; r.z = a.z - b.z; return r;
}

__device__ __forceinline__ F3 crossn(F3 a, F3 b) {
#pragma clang fp contract(off)
    F3 c;
    c.x = a.y * b.z - a.z * b.y;
    c.y = a.z * b.x - a.x * b.z;
    c.z = a.x * b.y - a.y * b.x;
    float n = sqrtf(c.x * c.x + c.y * c.y + c.z * c.z) + 1e-6f;
    c.x = c.x / n; c.y = c.y / n; c.z = c.z / n;
    return c;
}

__device__ __forceinline__ F3 surfNormal(const float* __restrict__ depth, const K9& Ki, int y, int x) {
#pragma clang fp contract(off)
    F3 ctr  = camAt(depth, Ki, y, x);
    F3 x0   = camAt(depth, Ki, y, x - 1);
    F3 x1   = camAt(depth, Ki, y, x + 1);
    F3 y0   = camAt(depth, Ki, y - 1, x);
    F3 y1   = camAt(depth, Ki, y + 1, x);
    F3 x0y0 = camAt(depth, Ki, y - 1, x - 1);
    F3 x0y1 = camAt(depth, Ki, y + 1, x - 1);
    F3 x1y0 = camAt(depth, Ki, y - 1, x + 1);
    F3 x1y1 = camAt(depth, Ki, y + 1, x + 1);
    F3 n0 = crossn(f3sub(x0, ctr),   f3sub(y0, ctr));
    F3 n1 = crossn(f3sub(x1, ctr),   f3sub(y1, ctr));
    F3 n2 = crossn(f3sub(x0y0, ctr), f3sub(x0y1, ctr));
    F3 n3 = crossn(f3sub(x1y0, ctr), f3sub(x1y1, ctr));
    F3 s;
    s.x = (((n0.x + n1.x) + n2.x) + n3.x) / 4.0f;
    s.y = (((n0.y + n1.y) + n2.y) + n3.y) / 4.0f;
    s.z = (((n0.z + n1.z) + n2.z) + n3.z) / 4.0f;
    float n = sqrtf(s.x * s.x + s.y * s.y + s.z * s.z) + 1e-6f;
    s.x = s.x / n; s.y = s.y / n; s.z = s.z / n;
    return s;
}

// ---------------- K1: region bitmaps + stored normals + per-row partials ----
__global__ __launch_bounds__(256) void k_row_region(
        const float* __restrict__ depth, const int* __restrict__ mask,
        const float* __restrict__ Kinv,
        u64* __restrict__ bitL, u64* __restrict__ bitR,
        unsigned char* __restrict__ wpfx, float4* __restrict__ normBuf,
        float* __restrict__ partials) {
    int y = blockIdx.x, t = threadIdx.x;
    __shared__ u64 wM[32];
    __shared__ u64 wE0[32], wE1[32];
    __shared__ u64 wU[32];
    __shared__ int wcum[33];
    __shared__ unsigned char pbA[256];
    __shared__ unsigned char pbB[256];

    // load this thread's 8 mask pixels (x = 8t .. 8t+7)
    const int4* mrow = reinterpret_cast<const int4*>(mask + (size_t)y * W);
    int4 a = mrow[t * 2], b = mrow[t * 2 + 1];
    unsigned mbyte =
        ((unsigned)(a.x != 0))      | ((unsigned)(a.y != 0) << 1) |
        ((unsigned)(a.z != 0) << 2) | ((unsigned)(a.w != 0) << 3) |
        ((unsigned)(b.x != 0) << 4) | ((unsigned)(b.y != 0) << 5) |
        ((unsigned)(b.z != 0) << 6) | ((unsigned)(b.w != 0) << 7);
    pbA[t] = (unsigned char)mbyte;
    __syncthreads();
    if (t < 32) wM[t] = reinterpret_cast<u64*>(pbA)[t];
    __syncthreads();
    if (t < 32) {
        u64 M  = wM[t];
        u64 Mn = (M >> 1) | ((t < 31) ? (wM[t + 1] << 63) : 0ull);  // m[x+1], pad 0
        wE0[t] = ~M & Mn;   // left edges  (grad == +1)
        wE1[t] = M & ~Mn;   // right edges (grad == -1)
    }
    __syncthreads();

    // 48-bit edge window covering pixels [8t-20, 8t+27]
    int base = t * 8 - SIDE;
    int wi = base >> 6;
    int ofs = base & 63;
    u64 l0 = (wi >= 0)    ? wE0[wi]     : 0ull;
    u64 l1 = (wi + 1 < 32)? wE0[wi + 1] : 0ull;
    u64 r0 = (wi >= 0)    ? wE1[wi]     : 0ull;
    u64 r1 = (wi + 1 < 32)? wE1[wi + 1] : 0ull;
    u64 winL = ofs ? ((l0 >> ofs) | (l1 << (64 - ofs))) : l0;
    u64 winR = ofs ? ((r0 >> ofs) | (r1 << (64 - ofs))) : r0;

    const u64 M41 = (1ull << 41) - 1;
    unsigned bL = 0, bR = 0;
#pragma unroll
    for (int j = 0; j < 8; ++j) {
        unsigned notm = (((mbyte >> j) & 1u) ^ 1u);
        unsigned dl = (((winL >> j) & M41) != 0ull) ? 1u : 0u;
        unsigned dr = (((winR >> j) & M41) != 0ull) ? 1u : 0u;
        bL |= (dl & notm) << j;
        bR |= (dr & notm) << j;
    }
    unsigned bAny = bL | bR;

    // pack region bitmaps to global + union words
    pbA[t] = (unsigned char)bL;
    pbB[t] = (unsigned char)bR;
    __syncthreads();
    if (t < 32) {
        u64 wl = reinterpret_cast<u64*>(pbA)[t];
        u64 wr2 = reinterpret_cast<u64*>(pbB)[t];
        bitL[(size_t)y * 32 + t] = wl;
        bitR[(size_t)y * 32 + t] = wr2;
        wU[t] = wl | wr2;
    }
    __syncthreads();
    if (t == 0) {
        int s = 0;
#pragma unroll
        for (int w = 0; w < 32; ++w) { wcum[w] = s; s += __popcll(wU[w]); }
        wcum[32] = s;
    }
    __syncthreads();
    if (wcum[32] == 0) {
        if (t == 0) {
#pragma unroll
            for (int k = 0; k < 8; ++k) partials[(size_t)y * 8 + k] = 0.f;
        }
        return;
    }
    if (t < 32) wpfx[(size_t)y * 32 + t] = (unsigned char)min(wcum[t], 255);

    // slot base = union-rank of this thread's first pixel
    int wslot = t >> 3;
    int lowbits = (t & 7) * 8;
    u64 lowmask = (lowbits == 0) ? 0ull : ((1ull << lowbits) - 1ull);
    int slot = wcum[wslot] + __popcll(wU[wslot] & lowmask);

    float acc[8];
#pragma unroll
    for (int k = 0; k < 8; ++k) acc[k] = 0.f;
    if (bAny) {
        K9 kk;
#pragma unroll
        for (int i = 0; i < 9; ++i) kk.k[i] = Kinv[i];
        for (int j = 0; j < 8; ++j) {
            if (!((bAny >> j) & 1u)) continue;
            int x = t * 8 + j;
            float nx = 0.f, ny = 0.f, nz = 0.f;
            if (x > 0 && x < W - 1 && y > 0 && y < H - 1) {
                F3 n = surfNormal(depth, kk, y, x);
                nx = n.x; ny = n.y; nz = n.z;
            }
            normBuf[(size_t)y * 64 + min(slot, 63)] = make_float4(nx, ny, nz, 0.f);
            slot++;
            if ((bL >> j) & 1u) { acc[0] += nx; acc[1] += ny; acc[2] += nz; acc[3] += 1.f; }
            if ((bR >> j) & 1u) { acc[4] += nx; acc[5] += ny; acc[6] += nz; acc[7] += 1.f; }
        }
    }
    // wave reduce then cross-wave (deterministic fixed tree)
    __shared__ float swred[4][8];
    int wave = t >> 6, lane = t & 63;
#pragma unroll
    for (int k = 0; k < 8; ++k) {
        float v = acc[k];
        for (int o = 32; o > 0; o >>= 1) v += __shfl_down(v, o, 64);
        if (lane == 0) swred[wave][k] = v;
    }
    __syncthreads();
    if (t == 0) {
#pragma unroll
        for (int k = 0; k < 8; ++k)
            partials[(size_t)y * 8 + k] = ((swred[0][k] + swred[1][k]) + swred[2][k]) + swred[3][k];
    }
}

// ---------------- K2: fused mean + inlier + scan + sample + rowInfo ---------
__device__ __forceinline__ int computePos(int i, int N) {
    if (N >= SS) {
        float t = ((float)i * (float)(N - 1)) / 1999.0f;  // float32 reference parity
        return (int)floorf(t);
    } else {
        return min(i, max(N - 1, 0));
    }
}

__global__ __launch_bounds__(1024) void k_fused_mid(
        const float* __restrict__ partials,
        u64* __restrict__ bitL, u64* __restrict__ bitR,
        const unsigned char* __restrict__ wpfx,
        const float4* __restrict__ normBuf,
        const float* __restrict__ depth,
        float4* __restrict__ rowInfo, int* __restrict__ rowValid) {
#pragma clang fp contract(off)
    int t = threadIdx.x;
    __shared__ float sMean[8];
    __shared__ float sWave[16][8];
    __shared__ int cntL[H], cntR[H];
    __shared__ int cumL[H + 1], cumR[H + 1];
    __shared__ int accLs[H], accLc[H], accRs[H], accRc[H];
    __shared__ int tsL[1024], tsR[1024];

    // ---- Phase A: reduce per-row partials -> normalized mean normals ----
    float acc[8];
#pragma unroll
    for (int k = 0; k < 8; ++k) acc[k] = 0.f;
    for (int i = t; i < H; i += 1024) {
        const float4* pr = reinterpret_cast<const float4*>(partials + (size_t)i * 8);
        float4 pa = pr[0], pb = pr[1];
        acc[0] += pa.x; acc[1] += pa.y; acc[2] += pa.z; acc[3] += pa.w;
        acc[4] += pb.x; acc[5] += pb.y; acc[6] += pb.z; acc[7] += pb.w;
    }
    int wave = t >> 6, lane = t & 63;
#pragma unroll
    for (int k = 0; k < 8; ++k) {
        float v = acc[k];
        for (int o = 32; o > 0; o >>= 1) v += __shfl_down(v, o, 64);
        if (lane == 0) sWave[wave][k] = v;
    }
    // init LDS row arrays while reduction settles
    for (int r = t; r < H; r += 1024) {
        cntL[r] = 0; cntR[r] = 0;
        accLs[r] = 0; accLc[r] = 0; accRs[r] = 0; accRc[r] = 0;
    }
    __syncthreads();
    if (t == 0) {
        float s[8];
#pragma unroll
        for (int k = 0; k < 8; ++k) {
            float v = 0.f;
            for (int w = 0; w < 16; ++w) v += sWave[w][k];
            s[k] = v;
        }
        {
            float cnt = fmaxf(s[3], 1.f);
            float mx = s[0] / cnt, my = s[1] / cnt, mz = s[2] / cnt;
            float n = sqrtf(mx * mx + my * my + mz * mz);
            float nn = fmaxf(n, 1e-12f);
            mx = mx / nn; my = my / nn; mz = mz / nn;
            float n2 = sqrtf(mx * mx + my * my + mz * mz);
            sMean[0] = mx; sMean[1] = my; sMean[2] = mz; sMean[3] = n2;
        }
        {
            float cnt = fmaxf(s[7], 1.f);
            float mx = s[4] / cnt, my = s[5] / cnt, mz = s[6] / cnt;
            float n = sqrtf(mx * mx + my * my + mz * mz);
            float nn = fmaxf(n, 1e-12f);
            mx = mx / nn; my = my / nn; mz = mz / nn;
            float n2 = sqrtf(mx * mx + my * my + mz * mz);
            sMean[4] = mx; sMean[5] = my; sMean[6] = mz; sMean[7] = n2;
        }
    }
    __syncthreads();
    float m0 = sMean[0], m1 = sMean[1], m2 = sMean[2], m3 = fmaxf(sMean[3], 1e-8f);
    float m4 = sMean[4], m5 = sMean[5], m6 = sMean[6], m7 = fmaxf(sMean[7], 1e-8f);

    // ---- Phase B: inlier test per (row, word) unit, bitmaps rewritten ----
    for (int u = t; u < H * 32; u += 1024) {
        u64 ul = bitL[u], ur = bitR[u];
        u64 uu = ul | ur;
        if (!uu) continue;
        int r = u >> 5;
        int slot = wpfx[u];
        const float4* nb = normBuf + (size_t)r * 64;
        u64 ol = 0, orr = 0;
        int cl = 0, cr = 0;
        while (uu) {
            int bpos = __ffsll(uu) - 1;
            uu &= uu - 1;
            float4 n = nb[min(slot, 63)];
            slot++;
            float nn = sqrtf(n.x * n.x + n.y * n.y + n.z * n.z);
            float dn = fmaxf(nn, 1e-8f);
            u64 bb = 1ull << bpos;
            if (ul & bb) {
                float dot = n.x * m0 + n.y * m1 + n.z * m2;
                float c = dot / (dn * m3);
                if (c > THRC) { ol |= bb; cl++; }
            }
            if (ur & bb) {
                float dot = n.x * m4 + n.y * m5 + n.z * m6;
                float c = dot / (dn * m7);
                if (c > THRC) { orr |= bb; cr++; }
            }
        }
        bitL[u] = ol; bitR[u] = orr;
        if (cl) atomicAdd(&cntL[r], cl);
        if (cr) atomicAdd(&cntR[r], cr);
    }
    __syncthreads();

    // ---- Phase C: scan row counts ----
    int r0 = 2 * t, r1 = 2 * t + 1;
    int c0L = (r0 < H) ? cntL[r0] : 0;
    int c0R = (r0 < H) ? cntR[r0] : 0;
    int c1L = (r1 < H) ? cntL[r1] : 0;
    int c1R = (r1 < H) ? cntR[r1] : 0;
    int sl = c0L + c1L, sr = c0R + c1R;
    tsL[t] = sl; tsR[t] = sr;
    __syncthreads();
    for (int off = 1; off < 1024; off <<= 1) {
        int vl = 0, vr = 0;
        if (t >= off) { vl = tsL[t - off]; vr = tsR[t - off]; }
        __syncthreads();
        tsL[t] += vl; tsR[t] += vr;
        __syncthreads();
    }
    int excL = tsL[t] - sl, excR = tsR[t] - sr;
    if (r0 < H) { cumL[r0] = excL;       cumR[r0] = excR; }
    if (r1 < H) { cumL[r1] = excL + c0L; cumR[r1] = excR + c0R; }
    if (t == 1023) { cumL[H] = tsL[1023]; cumR[H] = tsR[1023]; }
    __syncthreads();
    int Nl = cumL[H], Nr = cumR[H];
    int vc = (Nl > 0 && Nr > 0) ? 1 : 0;

    // ---- Phase D: sampling (rank-select k-th inlier) -> LDS row accums ----
    if (vc) {
        for (int i = t; i < SS; i += 1024) {
            int pos = computePos(i, Nl);
            int lo = 0, hi = H + 1;
            while (lo < hi) { int mid = (lo + hi) >> 1; if (cumL[mid] <= pos) lo = mid + 1; else hi = mid; }
            int row = lo - 1;
            int k = pos - cumL[row];
            const u64* wr = bitL + (size_t)row * 32;
            int c = 0, x = 0;
            for (int wj = 0; wj < 32; ++wj) {
                u64 w = wr[wj];
                int pc = __popcll(w);
                if (c + pc > k) {
                    int need = k - c;
                    while (need--) w &= (w - 1);
                    x = wj * 64 + (__ffsll((unsigned long long)w) - 1);
                    break;
                }
                c += pc;
            }
            atomicAdd(&accLs[row], x);
            atomicAdd(&accLc[row], 1);
        }
        for (int i = t; i < SS; i += 1024) {
            int pos = computePos(i, Nr);
            int lo = 0, hi = H + 1;
            while (lo < hi) { int mid = (lo + hi) >> 1; if (cumR[mid] <= pos) lo = mid + 1; else hi = mid; }
            int row = lo - 1;
            int k = pos - cumR[row];
            const u64* wr = bitR + (size_t)row * 32;
            int c = 0, x = 0;
            for (int wj = 0; wj < 32; ++wj) {
                u64 w = wr[wj];
                int pc = __popcll(w);
                if (c + pc > k) {
                    int need = k - c;
                    while (need--) w &= (w - 1);
                    x = wj * 64 + (__ffsll((unsigned long long)w) - 1);
                    break;
                }
                c += pc;
            }
            atomicAdd(&accRs[row], x);
            atomicAdd(&accRc[row], 1);
        }
    }
    __syncthreads();

    // ---- Phase E: per-row interpolation endpoints ----
    for (int r = t; r < H; r += 1024) {
        int lc = accLc[r], rc = accRc[r];
        float lmean = (float)accLs[r] / fmaxf((float)lc, 1.0f);
        float rmean = (float)accRs[r] / fmaxf((float)rc, 1.0f);
        int lx = min(max((int)rintf(lmean), 0), W - 1);
        int rx = min(max((int)rintf(rmean), 0), W - 1);
        float ld = depth[(size_t)r * W + lx], rd = depth[(size_t)r * W + rx];
        int valid = (lc > 0) && (rc > 0) && vc && (!isnan(ld)) && (!isnan(rd));
        rowInfo[r] = make_float4((float)lx, (float)rx, ld, rd);
        rowValid[r] = valid;
    }
}

// ---------------- K3: per-row interpolation + output ------------------------
__global__ __launch_bounds__(256) void k_out(
        const float* __restrict__ depth, const int* __restrict__ mask,
        const float4* __restrict__ rowInfo, const int* __restrict__ rowValid,
        float* __restrict__ out) {
#pragma clang fp contract(off)
    int y = blockIdx.x, t = threadIdx.x;
    const int4* mrow = reinterpret_cast<const int4*>(mask + (size_t)y * W);
    const float4* drow = reinterpret_cast<const float4*>(depth + (size_t)y * W);
    int4 ma = mrow[2 * t], mb = mrow[2 * t + 1];
    float4 da = drow[2 * t], db = drow[2 * t + 1];
    int any = ma.x | ma.y | ma.z | ma.w | mb.x | mb.y | mb.z | mb.w;
    int rowAny = __syncthreads_or(any != 0);
    float4 info = rowInfo[y];
    int valid = rowValid[y] && rowAny;
    float slx = info.x, srx = info.y, sld = info.z, srd = info.w;
    float denom = (srx - slx) + 1e-6f;

    int   m8[8] = { ma.x, ma.y, ma.z, ma.w, mb.x, mb.y, mb.z, mb.w };
    float d8[8] = { da.x, da.y, da.z, da.w, db.x, db.y, db.z, db.w };
    float o8[8];
    int xb = t * 8;
#pragma unroll
    for (int j = 0; j < 8; ++j) {
        float o = d8[j];
        if (valid && m8[j]) {
            float r = ((float)(xb + j) - slx) / denom;
            r = fminf(fmaxf(r, 0.0f), 1.0f);
            o = (1.0f - r) * sld + r * srd;
        }
        o8[j] = o;
    }
    float4* orow = reinterpret_cast<float4*>(out + (size_t)y * W);
    orow[2 * t]     = make_float4(o8[0], o8[1], o8[2], o8[3]);
    orow[2 * t + 1] = make_float4(o8[4], o8[5], o8[6], o8[7]);
}

// ---------------- launcher ---------------------------------------------------
extern "C" void kernel_launch(void* const* d_in, const int* in_sizes, int n_in,
                              void* d_out, int out_size, void* d_ws, size_t ws_size,
                              hipStream_t stream) {
    const float* depth = (const float*)d_in[0];
    const int*   mask  = (const int*)d_in[1];
    const float* Kinv  = (const float*)d_in[2];
    float* out = (float*)d_out;
    char* ws = (char*)d_ws;

    u64* bitL = (u64*)(ws + OFF_BITL);
    u64* bitR = (u64*)(ws + OFF_BITR);
    float* partials = (float*)(ws + OFF_PART);
    unsigned char* wpfx = (unsigned char*)(ws + OFF_WPFX);
    float4* normBuf = (float4*)(ws + OFF_NORM);
    float4* rowInfo = (float4*)(ws + OFF_INFO);
    int* rowValid = (int*)(ws + OFF_VALID);

    k_row_region<<<H, 256, 0, stream>>>(depth, mask, Kinv, bitL, bitR, wpfx, normBuf, partials);
    k_fused_mid<<<1, 1024, 0, stream>>>(partials, bitL, bitR, wpfx, normBuf, depth, rowInfo, rowValid);
    k_out<<<H, 256, 0, stream>>>(depth, mask, rowInfo, rowValid, out);
}

// Round 5
// 69.439 us; speedup vs baseline: 5.3374x; 5.3374x over previous
//
#include <hip/hip_runtime.h>
#include <math.h>

#define H 1536
#define W 2048
#define NPIX (H*W)
#define SS 2000
#define SIDE 20
#define THRC 0.2f

typedef unsigned long long u64;

// ---------------- workspace layout (bytes) ----------------
constexpr size_t OFF_BITL  = 0;                              // u64[H*32]   384 KB (region -> inlier bitmaps)
constexpr size_t OFF_BITR  = OFF_BITL + (size_t)H*32*8;      // u64[H*32]   384 KB
constexpr size_t OFF_PART  = OFF_BITR + (size_t)H*32*8;      // float[H*8]   48 KB
constexpr size_t OFF_MEANS = OFF_PART + (size_t)H*8*4;       // float[8]
constexpr size_t OFF_CNTL  = OFF_MEANS + 64;                 // int[H]
constexpr size_t OFF_CNTR  = OFF_CNTL + (size_t)H*4;         // int[H]
constexpr size_t OFF_NORM  = OFF_CNTR + (size_t)H*4;         // float4[H*64] 1.5 MB (per-flagged-pixel normals)
constexpr size_t OFF_INFO  = OFF_NORM + (size_t)H*64*16;     // float4[H]    24 KB {lx, rx, ld, rd}
constexpr size_t OFF_VALID = OFF_INFO + (size_t)H*16;        // int[H]        6 KB

// ---------------- math helpers (contract off: match numpy per-op rounding) ----
struct F3 { float x, y, z; };
struct K9 { float k[9]; };

__device__ __forceinline__ F3 camAt(const float* __restrict__ depth, const K9& Ki, int y, int x) {
#pragma clang fp contract(off)
    float d = depth[y * W + x];
    float u = (float)x, v = (float)y;
    F3 p;
    p.x = (Ki.k[0] * u + Ki.k[1] * v + Ki.k[2]) * d;
    p.y = (Ki.k[3] * u + Ki.k[4] * v + Ki.k[5]) * d;
    p.z = (Ki.k[6] * u + Ki.k[7] * v + Ki.k[8]) * d;
    return p;
}

__device__ __forceinline__ F3 f3sub(F3 a, F3 b) {
#pragma clang fp contract(off)
    F3 r; r.x = a.x - b.x; r.y = a.y - b.y; r.z = a.z - b.z; return r;
}

__device__ __forceinline__ F3 crossn(F3 a, F3 b) {
#pragma clang fp contract(off)
    F3 c;
    c.x = a.y * b.z - a.z * b.y;
    c.y = a.z * b.x - a.x * b.z;
    c.z = a.x * b.y - a.y * b.x;
    float n = sqrtf(c.x * c.x + c.y * c.y + c.z * c.z) + 1e-6f;
    c.x = c.x / n; c.y = c.y / n; c.z = c.z / n;
    return c;
}

__device__ __forceinline__ F3 surfNormal(const float* __restrict__ depth, const K9& Ki, int y, int x) {
#pragma clang fp contract(off)
    F3 ctr  = camAt(depth, Ki, y, x);
    F3 x0   = camAt(depth, Ki, y, x - 1);
    F3 x1   = camAt(depth, Ki, y, x + 1);
    F3 y0   = camAt(depth, Ki, y - 1, x);
    F3 y1   = camAt(depth, Ki, y + 1, x);
    F3 x0y0 = camAt(depth, Ki, y - 1, x - 1);
    F3 x0y1 = camAt(depth, Ki, y + 1, x - 1);
    F3 x1y0 = camAt(depth, Ki, y - 1, x + 1);
    F3 x1y1 = camAt(depth, Ki, y + 1, x + 1);
    F3 n0 = crossn(f3sub(x0, ctr),   f3sub(y0, ctr));
    F3 n1 = crossn(f3sub(x1, ctr),   f3sub(y1, ctr));
    F3 n2 = crossn(f3sub(x0y0, ctr), f3sub(x0y1, ctr));
    F3 n3 = crossn(f3sub(x1y0, ctr), f3sub(x1y1, ctr));
    F3 s;
    s.x = (((n0.x + n1.x) + n2.x) + n3.x) / 4.0f;
    s.y = (((n0.y + n1.y) + n2.y) + n3.y) / 4.0f;
    s.z = (((n0.z + n1.z) + n2.z) + n3.z) / 4.0f;
    float n = sqrtf(s.x * s.x + s.y * s.y + s.z * s.z) + 1e-6f;
    s.x = s.x / n; s.y = s.y / n; s.z = s.z / n;
    return s;
}

// ---------------- K1: region bitmaps + stored normals + per-row partials ----
__global__ __launch_bounds__(256) void k_row_region(
        const float* __restrict__ depth, const int* __restrict__ mask,
        const float* __restrict__ Kinv,
        u64* __restrict__ bitL, u64* __restrict__ bitR,
        float4* __restrict__ normBuf,
        float* __restrict__ partials) {
    int y = blockIdx.x, t = threadIdx.x;
    __shared__ u64 wM[32];
    __shared__ u64 wE0[32], wE1[32];
    __shared__ u64 wU[32];
    __shared__ int wcum[33];
    __shared__ unsigned char pbA[256];
    __shared__ unsigned char pbB[256];

    // load this thread's 8 mask pixels (x = 8t .. 8t+7)
    const int4* mrow = reinterpret_cast<const int4*>(mask + (size_t)y * W);
    int4 a = mrow[t * 2], b = mrow[t * 2 + 1];
    unsigned mbyte =
        ((unsigned)(a.x != 0))      | ((unsigned)(a.y != 0) << 1) |
        ((unsigned)(a.z != 0) << 2) | ((unsigned)(a.w != 0) << 3) |
        ((unsigned)(b.x != 0) << 4) | ((unsigned)(b.y != 0) << 5) |
        ((unsigned)(b.z != 0) << 6) | ((unsigned)(b.w != 0) << 7);
    pbA[t] = (unsigned char)mbyte;
    __syncthreads();
    if (t < 32) wM[t] = reinterpret_cast<u64*>(pbA)[t];
    __syncthreads();
    if (t < 32) {
        u64 M  = wM[t];
        u64 Mn = (M >> 1) | ((t < 31) ? (wM[t + 1] << 63) : 0ull);  // m[x+1], pad 0
        wE0[t] = ~M & Mn;   // left edges  (grad == +1)
        wE1[t] = M & ~Mn;   // right edges (grad == -1)
    }
    __syncthreads();

    // 48-bit edge window covering pixels [8t-20, 8t+27]
    int base = t * 8 - SIDE;
    int wi = base >> 6;
    int ofs = base & 63;
    u64 l0 = (wi >= 0)    ? wE0[wi]     : 0ull;
    u64 l1 = (wi + 1 < 32)? wE0[wi + 1] : 0ull;
    u64 r0 = (wi >= 0)    ? wE1[wi]     : 0ull;
    u64 r1 = (wi + 1 < 32)? wE1[wi + 1] : 0ull;
    u64 winL = ofs ? ((l0 >> ofs) | (l1 << (64 - ofs))) : l0;
    u64 winR = ofs ? ((r0 >> ofs) | (r1 << (64 - ofs))) : r0;

    const u64 M41 = (1ull << 41) - 1;
    unsigned bL = 0, bR = 0;
#pragma unroll
    for (int j = 0; j < 8; ++j) {
        unsigned notm = (((mbyte >> j) & 1u) ^ 1u);
        unsigned dl = (((winL >> j) & M41) != 0ull) ? 1u : 0u;
        unsigned dr = (((winR >> j) & M41) != 0ull) ? 1u : 0u;
        bL |= (dl & notm) << j;
        bR |= (dr & notm) << j;
    }
    unsigned bAny = bL | bR;

    // pack region bitmaps to global + union words
    pbA[t] = (unsigned char)bL;
    pbB[t] = (unsigned char)bR;
    __syncthreads();
    if (t < 32) {
        u64 wl = reinterpret_cast<u64*>(pbA)[t];
        u64 wr2 = reinterpret_cast<u64*>(pbB)[t];
        bitL[(size_t)y * 32 + t] = wl;
        bitR[(size_t)y * 32 + t] = wr2;
        wU[t] = wl | wr2;
    }
    __syncthreads();
    if (t == 0) {
        int s = 0;
#pragma unroll
        for (int w = 0; w < 32; ++w) { wcum[w] = s; s += __popcll(wU[w]); }
        wcum[32] = s;
    }
    __syncthreads();
    if (wcum[32] == 0) {
        if (t == 0) {
#pragma unroll
            for (int k = 0; k < 8; ++k) partials[(size_t)y * 8 + k] = 0.f;
        }
        return;
    }

    // slot base = union-rank of this thread's first pixel
    int wslot = t >> 3;
    int lowbits = (t & 7) * 8;
    u64 lowmask = (lowbits == 0) ? 0ull : ((1ull << lowbits) - 1ull);
    int slot = wcum[wslot] + __popcll(wU[wslot] & lowmask);

    float acc[8];
#pragma unroll
    for (int k = 0; k < 8; ++k) acc[k] = 0.f;
    if (bAny) {
        K9 kk;
#pragma unroll
        for (int i = 0; i < 9; ++i) kk.k[i] = Kinv[i];
        for (int j = 0; j < 8; ++j) {
            if (!((bAny >> j) & 1u)) continue;
            int x = t * 8 + j;
            float nx = 0.f, ny = 0.f, nz = 0.f;
            if (x > 0 && x < W - 1 && y > 0 && y < H - 1) {
                F3 n = surfNormal(depth, kk, y, x);
                nx = n.x; ny = n.y; nz = n.z;
            }
            normBuf[(size_t)y * 64 + min(slot, 63)] = make_float4(nx, ny, nz, 0.f);
            slot++;
            if ((bL >> j) & 1u) { acc[0] += nx; acc[1] += ny; acc[2] += nz; acc[3] += 1.f; }
            if ((bR >> j) & 1u) { acc[4] += nx; acc[5] += ny; acc[6] += nz; acc[7] += 1.f; }
        }
    }
    // wave reduce then cross-wave (deterministic fixed tree)
    __shared__ float swred[4][8];
    int wave = t >> 6, lane = t & 63;
#pragma unroll
    for (int k = 0; k < 8; ++k) {
        float v = acc[k];
        for (int o = 32; o > 0; o >>= 1) v += __shfl_down(v, o, 64);
        if (lane == 0) swred[wave][k] = v;
    }
    __syncthreads();
    if (t == 0) {
#pragma unroll
        for (int k = 0; k < 8; ++k)
            partials[(size_t)y * 8 + k] = ((swred[0][k] + swred[1][k]) + swred[2][k]) + swred[3][k];
    }
}

// ---------------- K2: reduce per-row partials -> normalized mean normals ----
__global__ __launch_bounds__(256) void k_mean(const float* __restrict__ partials,
                                              float* __restrict__ means) {
#pragma clang fp contract(off)
    __shared__ float sred[256][8];
    float acc[8];
#pragma unroll
    for (int k = 0; k < 8; ++k) acc[k] = 0.f;
    for (int i = threadIdx.x; i < H; i += 256) {
        const float4* pr = reinterpret_cast<const float4*>(partials + (size_t)i * 8);
        float4 pa = pr[0], pb = pr[1];
        acc[0] += pa.x; acc[1] += pa.y; acc[2] += pa.z; acc[3] += pa.w;
        acc[4] += pb.x; acc[5] += pb.y; acc[6] += pb.z; acc[7] += pb.w;
    }
#pragma unroll
    for (int k = 0; k < 8; ++k) sred[threadIdx.x][k] = acc[k];
    __syncthreads();
    for (int s = 128; s > 0; s >>= 1) {
        if (threadIdx.x < s) {
#pragma unroll
            for (int k = 0; k < 8; ++k) sred[threadIdx.x][k] += sred[threadIdx.x + s][k];
        }
        __syncthreads();
    }
    if (threadIdx.x == 0) {
        {
            float cnt = fmaxf(sred[0][3], 1.f);
            float mx = sred[0][0] / cnt, my = sred[0][1] / cnt, mz = sred[0][2] / cnt;
            float n = sqrtf(mx * mx + my * my + mz * mz);
            float nn = fmaxf(n, 1e-12f);
            mx = mx / nn; my = my / nn; mz = mz / nn;
            float n2 = sqrtf(mx * mx + my * my + mz * mz);
            means[0] = mx; means[1] = my; means[2] = mz; means[3] = n2;
        }
        {
            float cnt = fmaxf(sred[0][7], 1.f);
            float mx = sred[0][4] / cnt, my = sred[0][5] / cnt, mz = sred[0][6] / cnt;
            float n = sqrtf(mx * mx + my * my + mz * mz);
            float nn = fmaxf(n, 1e-12f);
            mx = mx / nn; my = my / nn; mz = mz / nn;
            float n2 = sqrtf(mx * mx + my * my + mz * mz);
            means[4] = mx; means[5] = my; means[6] = mz; means[7] = n2;
        }
    }
}

// ---------------- K3: 1-wave-per-row inlier test from stored normals --------
__global__ __launch_bounds__(64) void k_row_inlier(
        const float* __restrict__ means,
        u64* __restrict__ bitL, u64* __restrict__ bitR,
        const float4* __restrict__ normBuf,
        int* __restrict__ cntL, int* __restrict__ cntR) {
#pragma clang fp contract(off)
    int y = blockIdx.x, t = threadIdx.x;  // 64 threads = 1 wave
    u64 ul = 0, ur = 0;
    if (t < 32) { ul = bitL[(size_t)y * 32 + t]; ur = bitR[(size_t)y * 32 + t]; }
    u64 uu = ul | ur;
    if (__ballot(uu != 0ull) == 0ull) {
        if (t == 0) { cntL[y] = 0; cntR[y] = 0; }
        return;
    }
    // wave-wide inclusive scan of per-word popcounts (pc=0 for t>=32)
    int pc = __popcll(uu);
    int pref = pc;
    for (int o = 1; o < 64; o <<= 1) {
        int v = __shfl_up(pref, o, 64);
        if (t >= o) pref += v;
    }
    int excl = pref - pc;
    int total = __shfl(pref, 31, 64);

    __shared__ u64 sUL[32], sUR[32];
    __shared__ u64 sOL[32], sOR[32];
    __shared__ int sExcl[33];
    __shared__ int sCnt[2];
    if (t < 32) { sUL[t] = ul; sUR[t] = ur; sOL[t] = 0; sOR[t] = 0; sExcl[t] = excl; }
    if (t == 31) sExcl[32] = excl + pc;
    if (t == 0) { sCnt[0] = 0; sCnt[1] = 0; }
    __syncthreads();

    if (t < min(total, 64)) {
        // find word w: sExcl[w] <= t < sExcl[w+1]
        int lo = 0, hi = 32;
        while (lo < hi) { int mid = (lo + hi + 1) >> 1; if (sExcl[mid] <= t) lo = mid; else hi = mid - 1; }
        int w = lo;
        int k = t - sExcl[w];
        u64 word = sUL[w] | sUR[w];
        u64 tmp = word;
        while (k--) tmp &= tmp - 1;
        int bpos = __ffsll((unsigned long long)tmp) - 1;
        u64 bb = 1ull << bpos;

        float4 n = normBuf[(size_t)y * 64 + t];   // coalesced: slot == union rank == t
        float nn = sqrtf(n.x * n.x + n.y * n.y + n.z * n.z);
        float dn = fmaxf(nn, 1e-8f);
        if (sUL[w] & bb) {
            float dot = n.x * means[0] + n.y * means[1] + n.z * means[2];
            float c = dot / (dn * fmaxf(means[3], 1e-8f));
            if (c > THRC) { atomicOr(&sOL[w], bb); atomicAdd(&sCnt[0], 1); }
        }
        if (sUR[w] & bb) {
            float dot = n.x * means[4] + n.y * means[5] + n.z * means[6];
            float c = dot / (dn * fmaxf(means[7], 1e-8f));
            if (c > THRC) { atomicOr(&sOR[w], bb); atomicAdd(&sCnt[1], 1); }
        }
    }
    __syncthreads();
    if (t < 32) {
        bitL[(size_t)y * 32 + t] = sOL[t];
        bitR[(size_t)y * 32 + t] = sOR[t];
    }
    if (t == 0) { cntL[y] = sCnt[0]; cntR[y] = sCnt[1]; }
}

// ---------------- K4: scan + sample + rowInfo (single block) ----------------
__device__ __forceinline__ int computePos(int i, int N) {
    if (N >= SS) {
        float t = ((float)i * (float)(N - 1)) / 1999.0f;  // float32 reference parity
        return (int)floorf(t);
    } else {
        return min(i, max(N - 1, 0));
    }
}

__global__ __launch_bounds__(1024) void k_scan_sample(
        const int* __restrict__ cntL, const int* __restrict__ cntR,
        const u64* __restrict__ bitL, const u64* __restrict__ bitR,
        const float* __restrict__ depth,
        float4* __restrict__ rowInfo, int* __restrict__ rowValid) {
#pragma clang fp contract(off)
    int t = threadIdx.x;  // 1024 threads
    __shared__ int tsL[1024], tsR[1024];
    __shared__ int cumL[H + 1], cumR[H + 1];
    __shared__ int accLs[H], accLc[H], accRs[H], accRc[H];
    for (int r = t; r < H; r += 1024) { accLs[r] = 0; accLc[r] = 0; accRs[r] = 0; accRc[r] = 0; }

    int r0 = 2 * t, r1 = 2 * t + 1;
    int c0L = (r0 < H) ? cntL[r0] : 0;
    int c0R = (r0 < H) ? cntR[r0] : 0;
    int c1L = (r1 < H) ? cntL[r1] : 0;
    int c1R = (r1 < H) ? cntR[r1] : 0;
    int sl = c0L + c1L, sr = c0R + c1R;
    tsL[t] = sl; tsR[t] = sr;
    __syncthreads();
    for (int off = 1; off < 1024; off <<= 1) {
        int vl = 0, vr = 0;
        if (t >= off) { vl = tsL[t - off]; vr = tsR[t - off]; }
        __syncthreads();
        tsL[t] += vl; tsR[t] += vr;
        __syncthreads();
    }
    int excL = tsL[t] - sl, excR = tsR[t] - sr;
    if (r0 < H) { cumL[r0] = excL;       cumR[r0] = excR; }
    if (r1 < H) { cumL[r1] = excL + c0L; cumR[r1] = excR + c0R; }
    if (t == 1023) { cumL[H] = tsL[1023]; cumR[H] = tsR[1023]; }
    __syncthreads();
    int Nl = cumL[H], Nr = cumR[H];
    int vc = (Nl > 0 && Nr > 0) ? 1 : 0;

    if (vc) {
        for (int i = t; i < SS; i += 1024) {
            int pos = computePos(i, Nl);
            int lo = 0, hi = H + 1;
            while (lo < hi) { int mid = (lo + hi) >> 1; if (cumL[mid] <= pos) lo = mid + 1; else hi = mid; }
            int row = lo - 1;
            int k = pos - cumL[row];
            const u64* wr = bitL + (size_t)row * 32;
            int c = 0, x = 0;
            for (int wj = 0; wj < 32; ++wj) {
                u64 w = wr[wj];
                int pc = __popcll(w);
                if (c + pc > k) {
                    int need = k - c;
                    while (need--) w &= (w - 1);
                    x = wj * 64 + (__ffsll((unsigned long long)w) - 1);
                    break;
                }
                c += pc;
            }
            atomicAdd(&accLs[row], x);
            atomicAdd(&accLc[row], 1);
        }
        for (int i = t; i < SS; i += 1024) {
            int pos = computePos(i, Nr);
            int lo = 0, hi = H + 1;
            while (lo < hi) { int mid = (lo + hi) >> 1; if (cumR[mid] <= pos) lo = mid + 1; else hi = mid; }
            int row = lo - 1;
            int k = pos - cumR[row];
            const u64* wr = bitR + (size_t)row * 32;
            int c = 0, x = 0;
            for (int wj = 0; wj < 32; ++wj) {
                u64 w = wr[wj];
                int pc = __popcll(w);
                if (c + pc > k) {
                    int need = k - c;
                    while (need--) w &= (w - 1);
                    x = wj * 64 + (__ffsll((unsigned long long)w) - 1);
                    break;
                }
                c += pc;
            }
            atomicAdd(&accRs[row], x);
            atomicAdd(&accRc[row], 1);
        }
    }
    __syncthreads();

    // per-row interpolation endpoints
    for (int r = t; r < H; r += 1024) {
        int lc = accLc[r], rc = accRc[r];
        float lmean = (float)accLs[r] / fmaxf((float)lc, 1.0f);
        float rmean = (float)accRs[r] / fmaxf((float)rc, 1.0f);
        int lx = min(max((int)rintf(lmean), 0), W - 1);
        int rx = min(max((int)rintf(rmean), 0), W - 1);
        float ld = depth[(size_t)r * W + lx], rd = depth[(size_t)r * W + rx];
        int valid = (lc > 0) && (rc > 0) && vc && (!isnan(ld)) && (!isnan(rd));
        rowInfo[r] = make_float4((float)lx, (float)rx, ld, rd);
        rowValid[r] = valid;
    }
}

// ---------------- K5: per-row interpolation + output ------------------------
__global__ __launch_bounds__(256) void k_out(
        const float* __restrict__ depth, const int* __restrict__ mask,
        const float4* __restrict__ rowInfo, const int* __restrict__ rowValid,
        float* __restrict__ out) {
#pragma clang fp contract(off)
    int y = blockIdx.x, t = threadIdx.x;
    const int4* mrow = reinterpret_cast<const int4*>(mask + (size_t)y * W);
    const float4* drow = reinterpret_cast<const float4*>(depth + (size_t)y * W);
    int4 ma = mrow[2 * t], mb = mrow[2 * t + 1];
    float4 da = drow[2 * t], db = drow[2 * t + 1];
    int any = ma.x | ma.y | ma.z | ma.w | mb.x | mb.y | mb.z | mb.w;
    int rowAny = __syncthreads_or(any != 0);
    float4 info = rowInfo[y];
    int valid = rowValid[y] && rowAny;
    float slx = info.x, srx = info.y, sld = info.z, srd = info.w;
    float denom = (srx - slx) + 1e-6f;

    int   m8[8] = { ma.x, ma.y, ma.z, ma.w, mb.x, mb.y, mb.z, mb.w };
    float d8[8] = { da.x, da.y, da.z, da.w, db.x, db.y, db.z, db.w };
    float o8[8];
    int xb = t * 8;
#pragma unroll
    for (int j = 0; j < 8; ++j) {
        float o = d8[j];
        if (valid && m8[j]) {
            float r = ((float)(xb + j) - slx) / denom;
            r = fminf(fmaxf(r, 0.0f), 1.0f);
            o = (1.0f - r) * sld + r * srd;
        }
        o8[j] = o;
    }
    float4* orow = reinterpret_cast<float4*>(out + (size_t)y * W);
    orow[2 * t]     = make_float4(o8[0], o8[1], o8[2], o8[3]);
    orow[2 * t + 1] = make_float4(o8[4], o8[5], o8[6], o8[7]);
}

// ---------------- launcher ---------------------------------------------------
extern "C" void kernel_launch(void* const* d_in, const int* in_sizes, int n_in,
                              void* d_out, int out_size, void* d_ws, size_t ws_size,
                              hipStream_t stream) {
    const float* depth = (const float*)d_in[0];
    const int*   mask  = (const int*)d_in[1];
    const float* Kinv  = (const float*)d_in[2];
    float* out = (float*)d_out;
    char* ws = (char*)d_ws;

    u64* bitL = (u64*)(ws + OFF_BITL);
    u64* bitR = (u64*)(ws + OFF_BITR);
    float* partials = (float*)(ws + OFF_PART);
    float* means    = (float*)(ws + OFF_MEANS);
    int* cntL = (int*)(ws + OFF_CNTL);
    int* cntR = (int*)(ws + OFF_CNTR);
    float4* normBuf = (float4*)(ws + OFF_NORM);
    float4* rowInfo = (float4*)(ws + OFF_INFO);
    int* rowValid = (int*)(ws + OFF_VALID);

    k_row_region<<<H, 256, 0, stream>>>(depth, mask, Kinv, bitL, bitR, normBuf, partials);
    k_mean<<<1, 256, 0, stream>>>(partials, means);
    k_row_inlier<<<H, 64, 0, stream>>>(means, bitL, bitR, normBuf, cntL, cntR);
    k_scan_sample<<<1, 1024, 0, stream>>>(cntL, cntR, bitL, bitR, depth, rowInfo, rowValid);
    k_out<<<H, 256, 0, stream>>>(depth, mask, rowInfo, rowValid, out);
}

// Round 6
// 36.904 us; speedup vs baseline: 10.0430x; 1.8816x over previous
//
#include <hip/hip_runtime.h>
#include <math.h>

#define H 1536
#define W 2048
#define NPIX (H*W)
#define SS 2000
#define SIDE 20
#define THRC 0.2f

typedef unsigned long long u64;
typedef unsigned short u16;

// ---------------- workspace layout (bytes) ----------------
constexpr size_t OFF_BITL  = 0;                              // u64[H*32]   384 KB (region bitmaps)
constexpr size_t OFF_BITR  = OFF_BITL + (size_t)H*32*8;      // u64[H*32]   384 KB
constexpr size_t OFF_MBITS = OFF_BITR + (size_t)H*32*8;      // u64[H*32]   384 KB (packed mask)
constexpr size_t OFF_PART  = OFF_MBITS + (size_t)H*32*8;     // float[H*8]   48 KB
constexpr size_t OFF_MEANS = OFF_PART + (size_t)H*8*4;       // float[8]
constexpr size_t OFF_CNTL  = OFF_MEANS + 64;                 // int[H]
constexpr size_t OFF_CNTR  = OFF_CNTL + (size_t)H*4;         // int[H]
constexpr size_t OFF_NORM  = OFF_CNTR + (size_t)H*4;         // float4[H*64] 1.5 MB
constexpr size_t OFF_XL    = OFF_NORM + (size_t)H*64*16;     // u16[H*64]   196 KB (inlier x lists)
constexpr size_t OFF_XR    = OFF_XL + (size_t)H*64*2;        // u16[H*64]   196 KB
constexpr size_t OFF_INFO  = OFF_XR + (size_t)H*64*2;        // float4[H]    24 KB {lx, rx, ld, rd}
constexpr size_t OFF_VALID = OFF_INFO + (size_t)H*16;        // int[H]        6 KB

// ---------------- math helpers (contract off: match numpy per-op rounding) ----
struct F3 { float x, y, z; };
struct K9 { float k[9]; };

__device__ __forceinline__ F3 camAt(const float* __restrict__ depth, const K9& Ki, int y, int x) {
#pragma clang fp contract(off)
    float d = depth[y * W + x];
    float u = (float)x, v = (float)y;
    F3 p;
    p.x = (Ki.k[0] * u + Ki.k[1] * v + Ki.k[2]) * d;
    p.y = (Ki.k[3] * u + Ki.k[4] * v + Ki.k[5]) * d;
    p.z = (Ki.k[6] * u + Ki.k[7] * v + Ki.k[8]) * d;
    return p;
}

__device__ __forceinline__ F3 f3sub(F3 a, F3 b) {
#pragma clang fp contract(off)
    F3 r; r.x = a.x - b.x; r.y = a.y - b.y; r.z = a.z - b.z; return r;
}

__device__ __forceinline__ F3 crossn(F3 a, F3 b) {
#pragma clang fp contract(off)
    F3 c;
    c.x = a.y * b.z - a.z * b.y;
    c.y = a.z * b.x - a.x * b.z;
    c.z = a.x * b.y - a.y * b.x;
    float n = sqrtf(c.x * c.x + c.y * c.y + c.z * c.z) + 1e-6f;
    c.x = c.x / n; c.y = c.y / n; c.z = c.z / n;
    return c;
}

__device__ __forceinline__ F3 surfNormal(const float* __restrict__ depth, const K9& Ki, int y, int x) {
#pragma clang fp contract(off)
    F3 ctr  = camAt(depth, Ki, y, x);
    F3 x0   = camAt(depth, Ki, y, x - 1);
    F3 x1   = camAt(depth, Ki, y, x + 1);
    F3 y0   = camAt(depth, Ki, y - 1, x);
    F3 y1   = camAt(depth, Ki, y + 1, x);
    F3 x0y0 = camAt(depth, Ki, y - 1, x - 1);
    F3 x0y1 = camAt(depth, Ki, y + 1, x - 1);
    F3 x1y0 = camAt(depth, Ki, y - 1, x + 1);
    F3 x1y1 = camAt(depth, Ki, y + 1, x + 1);
    F3 n0 = crossn(f3sub(x0, ctr),   f3sub(y0, ctr));
    F3 n1 = crossn(f3sub(x1, ctr),   f3sub(y1, ctr));
    F3 n2 = crossn(f3sub(x0y0, ctr), f3sub(x0y1, ctr));
    F3 n3 = crossn(f3sub(x1y0, ctr), f3sub(x1y1, ctr));
    F3 s;
    s.x = (((n0.x + n1.x) + n2.x) + n3.x) / 4.0f;
    s.y = (((n0.y + n1.y) + n2.y) + n3.y) / 4.0f;
    s.z = (((n0.z + n1.z) + n2.z) + n3.z) / 4.0f;
    float n = sqrtf(s.x * s.x + s.y * s.y + s.z * s.z) + 1e-6f;
    s.x = s.x / n; s.y = s.y / n; s.z = s.z / n;
    return s;
}

// ---------------- K1: region bitmaps + packed mask + lane-parallel normals --
__global__ __launch_bounds__(256) void k_row_region(
        const float* __restrict__ depth, const int* __restrict__ mask,
        const float* __restrict__ Kinv,
        u64* __restrict__ bitL, u64* __restrict__ bitR, u64* __restrict__ maskBits,
        float4* __restrict__ normBuf, float* __restrict__ partials) {
    int y = blockIdx.x, t = threadIdx.x;
    __shared__ u64 wM[32], wE0[32], wE1[32], wU[32], sBL[32], sBR[32];
    __shared__ int wcum[33];
    __shared__ unsigned char pbA[256], pbB[256];

    // load this thread's 8 mask pixels (x = 8t .. 8t+7)
    const int4* mrow = reinterpret_cast<const int4*>(mask + (size_t)y * W);
    int4 a = mrow[t * 2], b = mrow[t * 2 + 1];
    unsigned mbyte =
        ((unsigned)(a.x != 0))      | ((unsigned)(a.y != 0) << 1) |
        ((unsigned)(a.z != 0) << 2) | ((unsigned)(a.w != 0) << 3) |
        ((unsigned)(b.x != 0) << 4) | ((unsigned)(b.y != 0) << 5) |
        ((unsigned)(b.z != 0) << 6) | ((unsigned)(b.w != 0) << 7);
    pbA[t] = (unsigned char)mbyte;
    __syncthreads();
    if (t < 32) wM[t] = reinterpret_cast<u64*>(pbA)[t];
    __syncthreads();
    if (t < 32) {
        u64 M  = wM[t];
        u64 Mn = (M >> 1) | ((t < 31) ? (wM[t + 1] << 63) : 0ull);  // m[x+1], pad 0
        wE0[t] = ~M & Mn;   // left edges  (grad == +1)
        wE1[t] = M & ~Mn;   // right edges (grad == -1)
        maskBits[(size_t)y * 32 + t] = M;
    }
    __syncthreads();

    // 48-bit edge window covering pixels [8t-20, 8t+27]
    int base = t * 8 - SIDE;
    int wi = base >> 6;
    int ofs = base & 63;
    u64 l0 = (wi >= 0)    ? wE0[wi]     : 0ull;
    u64 l1 = (wi + 1 < 32)? wE0[wi + 1] : 0ull;
    u64 r0 = (wi >= 0)    ? wE1[wi]     : 0ull;
    u64 r1 = (wi + 1 < 32)? wE1[wi + 1] : 0ull;
    u64 winL = ofs ? ((l0 >> ofs) | (l1 << (64 - ofs))) : l0;
    u64 winR = ofs ? ((r0 >> ofs) | (r1 << (64 - ofs))) : r0;

    const u64 M41 = (1ull << 41) - 1;
    unsigned bL = 0, bR = 0;
#pragma unroll
    for (int j = 0; j < 8; ++j) {
        unsigned notm = (((mbyte >> j) & 1u) ^ 1u);
        unsigned dl = (((winL >> j) & M41) != 0ull) ? 1u : 0u;
        unsigned dr = (((winR >> j) & M41) != 0ull) ? 1u : 0u;
        bL |= (dl & notm) << j;
        bR |= (dr & notm) << j;
    }

    // pack region bitmaps to global + union words
    pbA[t] = (unsigned char)bL;
    pbB[t] = (unsigned char)bR;
    __syncthreads();
    if (t < 32) {
        u64 wl = reinterpret_cast<u64*>(pbA)[t];
        u64 wr2 = reinterpret_cast<u64*>(pbB)[t];
        bitL[(size_t)y * 32 + t] = wl;
        bitR[(size_t)y * 32 + t] = wr2;
        sBL[t] = wl; sBR[t] = wr2; wU[t] = wl | wr2;
    }
    __syncthreads();
    if (t == 0) {
        int s = 0;
#pragma unroll
        for (int w = 0; w < 32; ++w) { wcum[w] = s; s += __popcll(wU[w]); }
        wcum[32] = s;
    }
    __syncthreads();
    int total = wcum[32];
    if (total == 0) {
        if (t == 0) {
#pragma unroll
            for (int k = 0; k < 8; ++k) partials[(size_t)y * 8 + k] = 0.f;
        }
        return;
    }
    if (t >= 64) return;  // wave 0 handles all flagged pixels (one lane each)

    float acc[8];
#pragma unroll
    for (int k = 0; k < 8; ++k) acc[k] = 0.f;

    if (t < min(total, 64)) {
        // union-rank t -> (word, bit): largest w with wcum[w] <= t
        int lo = 0, hi = 33;
        while (lo < hi) { int mid = (lo + hi) >> 1; if (wcum[mid] <= t) lo = mid + 1; else hi = mid; }
        int w = lo - 1;
        int k = t - wcum[w];
        u64 tmp = wU[w];
        while (k--) tmp &= tmp - 1;
        int bpos = __ffsll((unsigned long long)tmp) - 1;
        int x = w * 64 + bpos;

        float nx = 0.f, ny = 0.f, nz = 0.f;
        if (x > 0 && x < W - 1 && y > 0 && y < H - 1) {
            K9 kk;
#pragma unroll
            for (int i = 0; i < 9; ++i) kk.k[i] = Kinv[i];
            F3 n = surfNormal(depth, kk, y, x);
            nx = n.x; ny = n.y; nz = n.z;
        }
        normBuf[(size_t)y * 64 + t] = make_float4(nx, ny, nz, 0.f);  // coalesced
        bool inL = (sBL[w] >> bpos) & 1ull;
        bool inR = (sBR[w] >> bpos) & 1ull;
        if (inL) { acc[0] += nx; acc[1] += ny; acc[2] += nz; acc[3] += 1.f; }
        if (inR) { acc[4] += nx; acc[5] += ny; acc[6] += nz; acc[7] += 1.f; }
    }
    // single-wave shfl reduction (deterministic fixed tree)
#pragma unroll
    for (int k = 0; k < 8; ++k) {
        float v = acc[k];
        for (int o = 32; o > 0; o >>= 1) v += __shfl_down(v, o, 64);
        acc[k] = v;
    }
    if (t == 0) {
#pragma unroll
        for (int k = 0; k < 8; ++k) partials[(size_t)y * 8 + k] = acc[k];
    }
}

// ---------------- K2: reduce per-row partials -> normalized mean normals ----
__global__ __launch_bounds__(256) void k_mean(const float* __restrict__ partials,
                                              float* __restrict__ means) {
#pragma clang fp contract(off)
    __shared__ float sW[4][8];
    int t = threadIdx.x;
    float acc[8];
#pragma unroll
    for (int k = 0; k < 8; ++k) acc[k] = 0.f;
    for (int i = t; i < H; i += 256) {
        const float4* pr = reinterpret_cast<const float4*>(partials + (size_t)i * 8);
        float4 pa = pr[0], pb = pr[1];
        acc[0] += pa.x; acc[1] += pa.y; acc[2] += pa.z; acc[3] += pa.w;
        acc[4] += pb.x; acc[5] += pb.y; acc[6] += pb.z; acc[7] += pb.w;
    }
    int wave = t >> 6, lane = t & 63;
#pragma unroll
    for (int k = 0; k < 8; ++k) {
        float v = acc[k];
        for (int o = 32; o > 0; o >>= 1) v += __shfl_down(v, o, 64);
        if (lane == 0) sW[wave][k] = v;
    }
    __syncthreads();
    if (t == 0) {
        float s[8];
#pragma unroll
        for (int k = 0; k < 8; ++k) s[k] = ((sW[0][k] + sW[1][k]) + sW[2][k]) + sW[3][k];
        {
            float cnt = fmaxf(s[3], 1.f);
            float mx = s[0] / cnt, my = s[1] / cnt, mz = s[2] / cnt;
            float n = sqrtf(mx * mx + my * my + mz * mz);
            float nn = fmaxf(n, 1e-12f);
            mx = mx / nn; my = my / nn; mz = mz / nn;
            float n2 = sqrtf(mx * mx + my * my + mz * mz);
            means[0] = mx; means[1] = my; means[2] = mz; means[3] = n2;
        }
        {
            float cnt = fmaxf(s[7], 1.f);
            float mx = s[4] / cnt, my = s[5] / cnt, mz = s[6] / cnt;
            float n = sqrtf(mx * mx + my * my + mz * mz);
            float nn = fmaxf(n, 1e-12f);
            mx = mx / nn; my = my / nn; mz = mz / nn;
            float n2 = sqrtf(mx * mx + my * my + mz * mz);
            means[4] = mx; means[5] = my; means[6] = mz; means[7] = n2;
        }
    }
}

// ---------------- K3: 1-wave-per-row inlier test -> compacted x lists -------
__global__ __launch_bounds__(64) void k_row_inlier(
        const float* __restrict__ means,
        const u64* __restrict__ bitL, const u64* __restrict__ bitR,
        const float4* __restrict__ normBuf,
        u16* __restrict__ xListL, u16* __restrict__ xListR,
        int* __restrict__ cntL, int* __restrict__ cntR) {
#pragma clang fp contract(off)
    int y = blockIdx.x, t = threadIdx.x;  // 64 threads = 1 wave
    u64 ul = 0, ur = 0;
    if (t < 32) { ul = bitL[(size_t)y * 32 + t]; ur = bitR[(size_t)y * 32 + t]; }
    u64 uu = ul | ur;
    if (__ballot(uu != 0ull) == 0ull) {
        if (t == 0) { cntL[y] = 0; cntR[y] = 0; }
        return;
    }
    // wave-wide inclusive scan of per-word popcounts (pc=0 for t>=32)
    int pc = __popcll(uu);
    int pref = pc;
    for (int o = 1; o < 64; o <<= 1) {
        int v = __shfl_up(pref, o, 64);
        if (t >= o) pref += v;
    }
    int excl = pref - pc;
    int total = __shfl(pref, 63, 64);

    __shared__ u64 sUL[32], sUR[32];
    __shared__ int sExcl[33];
    if (t < 32) { sUL[t] = ul; sUR[t] = ur; sExcl[t] = excl; }
    if (t == 31) sExcl[32] = pref;
    __syncthreads();

    bool iL = false, iR = false;
    int x = 0;
    if (t < min(total, 64)) {
        int lo = 0, hi = 33;
        while (lo < hi) { int mid = (lo + hi) >> 1; if (sExcl[mid] <= t) lo = mid + 1; else hi = mid; }
        int w = lo - 1;
        int k = t - sExcl[w];
        u64 tmp = sUL[w] | sUR[w];
        while (k--) tmp &= tmp - 1;
        int bpos = __ffsll((unsigned long long)tmp) - 1;
        u64 bb = 1ull << bpos;
        x = w * 64 + bpos;

        float4 n = normBuf[(size_t)y * 64 + t];   // coalesced: slot == union rank == t
        float nn = sqrtf(n.x * n.x + n.y * n.y + n.z * n.z);
        float dn = fmaxf(nn, 1e-8f);
        if (sUL[w] & bb) {
            float dot = n.x * means[0] + n.y * means[1] + n.z * means[2];
            float c = dot / (dn * fmaxf(means[3], 1e-8f));
            iL = c > THRC;
        }
        if (sUR[w] & bb) {
            float dot = n.x * means[4] + n.y * means[5] + n.z * means[6];
            float c = dot / (dn * fmaxf(means[7], 1e-8f));
            iR = c > THRC;
        }
    }
    u64 balL = __ballot(iL), balR = __ballot(iR);
    u64 lm = (t == 0) ? 0ull : ((~0ull) >> (64 - t));
    if (iL) xListL[(size_t)y * 64 + __popcll(balL & lm)] = (u16)x;  // ascending x
    if (iR) xListR[(size_t)y * 64 + __popcll(balR & lm)] = (u16)x;
    if (t == 0) { cntL[y] = (int)__popcll(balL); cntR[y] = (int)__popcll(balR); }
}

// ---------------- K4: wave-scan + O(1) sampling + rowInfo (single block) ----
__device__ __forceinline__ int computePos(int i, int N) {
    if (N >= SS) {
        float t = ((float)i * (float)(N - 1)) / 1999.0f;  // float32 reference parity
        return (int)floorf(t);
    } else {
        return min(i, max(N - 1, 0));
    }
}

__global__ __launch_bounds__(1024) void k_scan_sample(
        const int* __restrict__ cntL, const int* __restrict__ cntR,
        const u16* __restrict__ xListL, const u16* __restrict__ xListR,
        const float* __restrict__ depth,
        float4* __restrict__ rowInfo, int* __restrict__ rowValid) {
#pragma clang fp contract(off)
    int t = threadIdx.x;  // 1024 threads
    __shared__ int cumL[H + 1], cumR[H + 1];
    __shared__ int accLs[H], accLc[H], accRs[H], accRc[H];
    for (int r = t; r < H; r += 1024) { accLs[r] = 0; accLc[r] = 0; accRs[r] = 0; accRc[r] = 0; }

    // single-wave scan: 64 lanes x 24 rows each
    if (t < 64) {
        int base = t * 24;
        int sl = 0, sr = 0;
        for (int j = 0; j < 24; ++j) { sl += cntL[base + j]; sr += cntR[base + j]; }
        int eL = sl, eR = sr;
        for (int o = 1; o < 64; o <<= 1) {
            int vl = __shfl_up(eL, o, 64), vr = __shfl_up(eR, o, 64);
            if (t >= o) { eL += vl; eR += vr; }
        }
        eL -= sl; eR -= sr;  // exclusive
        int rl = eL, rr = eR;
        for (int j = 0; j < 24; ++j) {
            cumL[base + j] = rl; rl += cntL[base + j];
            cumR[base + j] = rr; rr += cntR[base + j];
        }
        if (t == 63) { cumL[H] = rl; cumR[H] = rr; }
    }
    __syncthreads();
    int Nl = cumL[H], Nr = cumR[H];
    int vc = (Nl > 0 && Nr > 0) ? 1 : 0;

    if (vc) {
        for (int i = t; i < SS; i += 1024) {
            int pos = computePos(i, Nl);
            int lo = 0, hi = H + 1;
            while (lo < hi) { int mid = (lo + hi) >> 1; if (cumL[mid] <= pos) lo = mid + 1; else hi = mid; }
            int row = lo - 1;
            int k = pos - cumL[row];
            int xv = (int)xListL[(size_t)row * 64 + k];
            atomicAdd(&accLs[row], xv);
            atomicAdd(&accLc[row], 1);
        }
        for (int i = t; i < SS; i += 1024) {
            int pos = computePos(i, Nr);
            int lo = 0, hi = H + 1;
            while (lo < hi) { int mid = (lo + hi) >> 1; if (cumR[mid] <= pos) lo = mid + 1; else hi = mid; }
            int row = lo - 1;
            int k = pos - cumR[row];
            int xv = (int)xListR[(size_t)row * 64 + k];
            atomicAdd(&accRs[row], xv);
            atomicAdd(&accRc[row], 1);
        }
    }
    __syncthreads();

    // per-row interpolation endpoints
    for (int r = t; r < H; r += 1024) {
        int lc = accLc[r], rc = accRc[r];
        float lmean = (float)accLs[r] / fmaxf((float)lc, 1.0f);
        float rmean = (float)accRs[r] / fmaxf((float)rc, 1.0f);
        int lx = min(max((int)rintf(lmean), 0), W - 1);
        int rx = min(max((int)rintf(rmean), 0), W - 1);
        float ld = depth[(size_t)r * W + lx], rd = depth[(size_t)r * W + rx];
        int valid = (lc > 0) && (rc > 0) && vc && (!isnan(ld)) && (!isnan(rd));
        rowInfo[r] = make_float4((float)lx, (float)rx, ld, rd);
        rowValid[r] = valid;
    }
}

// ---------------- K5: per-row interpolation + output (bit-mask input) -------
__global__ __launch_bounds__(256) void k_out(
        const float* __restrict__ depth, const u64* __restrict__ maskBits,
        const float4* __restrict__ rowInfo, const int* __restrict__ rowValid,
        float* __restrict__ out) {
#pragma clang fp contract(off)
    int y = blockIdx.x, t = threadIdx.x;
    u64 word = maskBits[(size_t)y * 32 + (t >> 3)];   // 8 threads share a word (broadcast)
    unsigned mbyte = (unsigned)((word >> ((t & 7) * 8)) & 0xFFull);
    int rowAny = __syncthreads_or(word != 0ull);      // t>>3 spans all 32 words

    const float4* drow = reinterpret_cast<const float4*>(depth + (size_t)y * W);
    float4 da = drow[2 * t], db = drow[2 * t + 1];

    float4 info = rowInfo[y];
    int valid = rowValid[y] && rowAny;
    float slx = info.x, srx = info.y, sld = info.z, srd = info.w;
    float denom = (srx - slx) + 1e-6f;

    float d8[8] = { da.x, da.y, da.z, da.w, db.x, db.y, db.z, db.w };
    float o8[8];
    int xb = t * 8;
#pragma unroll
    for (int j = 0; j < 8; ++j) {
        float o = d8[j];
        if (valid && ((mbyte >> j) & 1u)) {
            float r = ((float)(xb + j) - slx) / denom;
            r = fminf(fmaxf(r, 0.0f), 1.0f);
            o = (1.0f - r) * sld + r * srd;
        }
        o8[j] = o;
    }
    float4* orow = reinterpret_cast<float4*>(out + (size_t)y * W);
    orow[2 * t]     = make_float4(o8[0], o8[1], o8[2], o8[3]);
    orow[2 * t + 1] = make_float4(o8[4], o8[5], o8[6], o8[7]);
}

// ---------------- launcher ---------------------------------------------------
extern "C" void kernel_launch(void* const* d_in, const int* in_sizes, int n_in,
                              void* d_out, int out_size, void* d_ws, size_t ws_size,
                              hipStream_t stream) {
    const float* depth = (const float*)d_in[0];
    const int*   mask  = (const int*)d_in[1];
    const float* Kinv  = (const float*)d_in[2];
    float* out = (float*)d_out;
    char* ws = (char*)d_ws;

    u64* bitL = (u64*)(ws + OFF_BITL);
    u64* bitR = (u64*)(ws + OFF_BITR);
    u64* maskBits = (u64*)(ws + OFF_MBITS);
    float* partials = (float*)(ws + OFF_PART);
    float* means    = (float*)(ws + OFF_MEANS);
    int* cntL = (int*)(ws + OFF_CNTL);
    int* cntR = (int*)(ws + OFF_CNTR);
    float4* normBuf = (float4*)(ws + OFF_NORM);
    u16* xListL = (u16*)(ws + OFF_XL);
    u16* xListR = (u16*)(ws + OFF_XR);
    float4* rowInfo = (float4*)(ws + OFF_INFO);
    int* rowValid = (int*)(ws + OFF_VALID);

    k_row_region<<<H, 256, 0, stream>>>(depth, mask, Kinv, bitL, bitR, maskBits, normBuf, partials);
    k_mean<<<1, 256, 0, stream>>>(partials, means);
    k_row_inlier<<<H, 64, 0, stream>>>(means, bitL, bitR, normBuf, xListL, xListR, cntL, cntR);
    k_scan_sample<<<1, 1024, 0, stream>>>(cntL, cntR, xListL, xListR, depth, rowInfo, rowValid);
    k_out<<<H, 256, 0, stream>>>(depth, maskBits, rowInfo, rowValid, out);
}

// Round 7
// 29.512 us; speedup vs baseline: 12.5583x; 1.2505x over previous
//
#include <hip/hip_runtime.h>
#include <math.h>

#define H 1536
#define W 2048
#define NPIX (H*W)
#define SS 2000
#define SIDE 20
#define THRC 0.2f

typedef unsigned long long u64;
typedef unsigned short u16;

// ---------------- workspace layout (bytes) ----------------
constexpr size_t OFF_BITL  = 0;                              // u64[H*32]   384 KB (region bitmaps)
constexpr size_t OFF_BITR  = OFF_BITL + (size_t)H*32*8;      // u64[H*32]   384 KB
constexpr size_t OFF_MBITS = OFF_BITR + (size_t)H*32*8;      // u64[H*32]   384 KB (packed mask)
constexpr size_t OFF_PART  = OFF_MBITS + (size_t)H*32*8;     // float[H*8]   48 KB
constexpr size_t OFF_CNTL  = OFF_PART + (size_t)H*8*4;       // int[H]
constexpr size_t OFF_CNTR  = OFF_CNTL + (size_t)H*4;         // int[H]
constexpr size_t OFF_NORM  = OFF_CNTR + (size_t)H*4;         // float4[H*64] 1.5 MB
constexpr size_t OFF_XL    = OFF_NORM + (size_t)H*64*16;     // u16[H*64]   196 KB (inlier x lists)
constexpr size_t OFF_XR    = OFF_XL + (size_t)H*64*2;        // u16[H*64]   196 KB

// ---------------- math helpers (contract off: match numpy per-op rounding) ----
struct F3 { float x, y, z; };
struct K9 { float k[9]; };

__device__ __forceinline__ F3 camAt(const float* __restrict__ depth, const K9& Ki, int y, int x) {
#pragma clang fp contract(off)
    float d = depth[y * W + x];
    float u = (float)x, v = (float)y;
    F3 p;
    p.x = (Ki.k[0] * u + Ki.k[1] * v + Ki.k[2]) * d;
    p.y = (Ki.k[3] * u + Ki.k[4] * v + Ki.k[5]) * d;
    p.z = (Ki.k[6] * u + Ki.k[7] * v + Ki.k[8]) * d;
    return p;
}

__device__ __forceinline__ F3 f3sub(F3 a, F3 b) {
#pragma clang fp contract(off)
    F3 r; r.x = a.x - b.x; r.y = a.y - b.y; r.z = a.z - b.z; return r;
}

__device__ __forceinline__ F3 crossn(F3 a, F3 b) {
#pragma clang fp contract(off)
    F3 c;
    c.x = a.y * b.z - a.z * b.y;
    c.y = a.z * b.x - a.x * b.z;
    c.z = a.x * b.y - a.y * b.x;
    float n = sqrtf(c.x * c.x + c.y * c.y + c.z * c.z) + 1e-6f;
    c.x = c.x / n; c.y = c.y / n; c.z = c.z / n;
    return c;
}

__device__ __forceinline__ F3 surfNormal(const float* __restrict__ depth, const K9& Ki, int y, int x) {
#pragma clang fp contract(off)
    F3 ctr  = camAt(depth, Ki, y, x);
    F3 x0   = camAt(depth, Ki, y, x - 1);
    F3 x1   = camAt(depth, Ki, y, x + 1);
    F3 y0   = camAt(depth, Ki, y - 1, x);
    F3 y1   = camAt(depth, Ki, y + 1, x);
    F3 x0y0 = camAt(depth, Ki, y - 1, x - 1);
    F3 x0y1 = camAt(depth, Ki, y + 1, x - 1);
    F3 x1y0 = camAt(depth, Ki, y - 1, x + 1);
    F3 x1y1 = camAt(depth, Ki, y + 1, x + 1);
    F3 n0 = crossn(f3sub(x0, ctr),   f3sub(y0, ctr));
    F3 n1 = crossn(f3sub(x1, ctr),   f3sub(y1, ctr));
    F3 n2 = crossn(f3sub(x0y0, ctr), f3sub(x0y1, ctr));
    F3 n3 = crossn(f3sub(x1y0, ctr), f3sub(x1y1, ctr));
    F3 s;
    s.x = (((n0.x + n1.x) + n2.x) + n3.x) / 4.0f;
    s.y = (((n0.y + n1.y) + n2.y) + n3.y) / 4.0f;
    s.z = (((n0.z + n1.z) + n2.z) + n3.z) / 4.0f;
    float n = sqrtf(s.x * s.x + s.y * s.y + s.z * s.z) + 1e-6f;
    s.x = s.x / n; s.y = s.y / n; s.z = s.z / n;
    return s;
}

// ---------------- K1: region bitmaps + packed mask + lane-parallel normals --
__global__ __launch_bounds__(256) void k_row_region(
        const float* __restrict__ depth, const int* __restrict__ mask,
        const float* __restrict__ Kinv,
        u64* __restrict__ bitL, u64* __restrict__ bitR, u64* __restrict__ maskBits,
        float4* __restrict__ normBuf, float* __restrict__ partials) {
    int y = blockIdx.x, t = threadIdx.x;
    __shared__ u64 wM[32], wE0[32], wE1[32], wU[32], sBL[32], sBR[32];
    __shared__ int wcum[33];
    __shared__ unsigned char pbA[256], pbB[256];

    // load this thread's 8 mask pixels (x = 8t .. 8t+7)
    const int4* mrow = reinterpret_cast<const int4*>(mask + (size_t)y * W);
    int4 a = mrow[t * 2], b = mrow[t * 2 + 1];
    unsigned mbyte =
        ((unsigned)(a.x != 0))      | ((unsigned)(a.y != 0) << 1) |
        ((unsigned)(a.z != 0) << 2) | ((unsigned)(a.w != 0) << 3) |
        ((unsigned)(b.x != 0) << 4) | ((unsigned)(b.y != 0) << 5) |
        ((unsigned)(b.z != 0) << 6) | ((unsigned)(b.w != 0) << 7);
    pbA[t] = (unsigned char)mbyte;
    __syncthreads();
    if (t < 32) wM[t] = reinterpret_cast<u64*>(pbA)[t];
    __syncthreads();
    if (t < 32) {
        u64 M  = wM[t];
        u64 Mn = (M >> 1) | ((t < 31) ? (wM[t + 1] << 63) : 0ull);  // m[x+1], pad 0
        wE0[t] = ~M & Mn;   // left edges  (grad == +1)
        wE1[t] = M & ~Mn;   // right edges (grad == -1)
        maskBits[(size_t)y * 32 + t] = M;
    }
    __syncthreads();

    // 48-bit edge window covering pixels [8t-20, 8t+27]
    int base = t * 8 - SIDE;
    int wi = base >> 6;
    int ofs = base & 63;
    u64 l0 = (wi >= 0)    ? wE0[wi]     : 0ull;
    u64 l1 = (wi + 1 < 32)? wE0[wi + 1] : 0ull;
    u64 r0 = (wi >= 0)    ? wE1[wi]     : 0ull;
    u64 r1 = (wi + 1 < 32)? wE1[wi + 1] : 0ull;
    u64 winL = ofs ? ((l0 >> ofs) | (l1 << (64 - ofs))) : l0;
    u64 winR = ofs ? ((r0 >> ofs) | (r1 << (64 - ofs))) : r0;

    const u64 M41 = (1ull << 41) - 1;
    unsigned bL = 0, bR = 0;
#pragma unroll
    for (int j = 0; j < 8; ++j) {
        unsigned notm = (((mbyte >> j) & 1u) ^ 1u);
        unsigned dl = (((winL >> j) & M41) != 0ull) ? 1u : 0u;
        unsigned dr = (((winR >> j) & M41) != 0ull) ? 1u : 0u;
        bL |= (dl & notm) << j;
        bR |= (dr & notm) << j;
    }

    // pack region bitmaps to global + union words
    pbA[t] = (unsigned char)bL;
    pbB[t] = (unsigned char)bR;
    __syncthreads();
    if (t < 32) {
        u64 wl = reinterpret_cast<u64*>(pbA)[t];
        u64 wr2 = reinterpret_cast<u64*>(pbB)[t];
        bitL[(size_t)y * 32 + t] = wl;
        bitR[(size_t)y * 32 + t] = wr2;
        sBL[t] = wl; sBR[t] = wr2; wU[t] = wl | wr2;
    }
    __syncthreads();
    if (t == 0) {
        int s = 0;
#pragma unroll
        for (int w = 0; w < 32; ++w) { wcum[w] = s; s += __popcll(wU[w]); }
        wcum[32] = s;
    }
    __syncthreads();
    int total = wcum[32];
    if (total == 0) {
        if (t == 0) {
#pragma unroll
            for (int k = 0; k < 8; ++k) partials[(size_t)y * 8 + k] = 0.f;
        }
        return;
    }
    if (t >= 64) return;  // wave 0 handles all flagged pixels (one lane each)

    float acc[8];
#pragma unroll
    for (int k = 0; k < 8; ++k) acc[k] = 0.f;

    if (t < min(total, 64)) {
        // union-rank t -> (word, bit): largest w with wcum[w] <= t
        int lo = 0, hi = 33;
        while (lo < hi) { int mid = (lo + hi) >> 1; if (wcum[mid] <= t) lo = mid + 1; else hi = mid; }
        int w = lo - 1;
        int k = t - wcum[w];
        u64 tmp = wU[w];
        while (k--) tmp &= tmp - 1;
        int bpos = __ffsll((unsigned long long)tmp) - 1;
        int x = w * 64 + bpos;

        float nx = 0.f, ny = 0.f, nz = 0.f;
        if (x > 0 && x < W - 1 && y > 0 && y < H - 1) {
            K9 kk;
#pragma unroll
            for (int i = 0; i < 9; ++i) kk.k[i] = Kinv[i];
            F3 n = surfNormal(depth, kk, y, x);
            nx = n.x; ny = n.y; nz = n.z;
        }
        normBuf[(size_t)y * 64 + t] = make_float4(nx, ny, nz, 0.f);  // coalesced
        bool inL = (sBL[w] >> bpos) & 1ull;
        bool inR = (sBR[w] >> bpos) & 1ull;
        if (inL) { acc[0] += nx; acc[1] += ny; acc[2] += nz; acc[3] += 1.f; }
        if (inR) { acc[4] += nx; acc[5] += ny; acc[6] += nz; acc[7] += 1.f; }
    }
    // single-wave shfl reduction (deterministic fixed tree)
#pragma unroll
    for (int k = 0; k < 8; ++k) {
        float v = acc[k];
        for (int o = 32; o > 0; o >>= 1) v += __shfl_down(v, o, 64);
        acc[k] = v;
    }
    if (t == 0) {
#pragma unroll
        for (int k = 0; k < 8; ++k) partials[(size_t)y * 8 + k] = acc[k];
    }
}

// ---------------- K2: redundant mean + 1-wave inlier -> compacted x lists ---
__global__ __launch_bounds__(256) void k_mean_inlier(
        const float* __restrict__ partials,
        const u64* __restrict__ bitL, const u64* __restrict__ bitR,
        const float4* __restrict__ normBuf,
        u16* __restrict__ xListL, u16* __restrict__ xListR,
        int* __restrict__ cntL, int* __restrict__ cntR) {
#pragma clang fp contract(off)
    int y = blockIdx.x, t = threadIdx.x;
    __shared__ u64 sUL[32], sUR[32];
    __shared__ int sExcl[33];
    __shared__ float sW[4][8];
    __shared__ float sMean[8];

    // wave 0: load row bitmaps + per-word exclusive ranks (before any barrier)
    u64 ul = 0, ur = 0;
    int total = 0;
    if (t < 64) {
        if (t < 32) { ul = bitL[(size_t)y * 32 + t]; ur = bitR[(size_t)y * 32 + t]; sUL[t] = ul; sUR[t] = ur; }
        u64 uu = ul | ur;
        int pc = __popcll(uu);
        int pref = pc;
        for (int o = 1; o < 64; o <<= 1) {
            int v = __shfl_up(pref, o, 64);
            if (t >= o) pref += v;
        }
        if (t < 32) sExcl[t] = pref - pc;
        if (t == 31) sExcl[32] = pref;
        total = __shfl(pref, 63, 64);
    }
    int any = __syncthreads_or((t < 32) && ((ul | ur) != 0ull));
    if (!any) {
        if (t == 0) { cntL[y] = 0; cntR[y] = 0; }
        return;
    }

    // ---- phase A: redundant global mean (structure identical to old k_mean) ----
    float acc[8];
#pragma unroll
    for (int k = 0; k < 8; ++k) acc[k] = 0.f;
    for (int i = t; i < H; i += 256) {
        const float4* pr = reinterpret_cast<const float4*>(partials + (size_t)i * 8);
        float4 pa = pr[0], pb = pr[1];
        acc[0] += pa.x; acc[1] += pa.y; acc[2] += pa.z; acc[3] += pa.w;
        acc[4] += pb.x; acc[5] += pb.y; acc[6] += pb.z; acc[7] += pb.w;
    }
    int wave = t >> 6, lane = t & 63;
#pragma unroll
    for (int k = 0; k < 8; ++k) {
        float v = acc[k];
        for (int o = 32; o > 0; o >>= 1) v += __shfl_down(v, o, 64);
        if (lane == 0) sW[wave][k] = v;
    }
    __syncthreads();
    if (t == 0) {
        float s[8];
#pragma unroll
        for (int k = 0; k < 8; ++k) s[k] = ((sW[0][k] + sW[1][k]) + sW[2][k]) + sW[3][k];
        {
            float cnt = fmaxf(s[3], 1.f);
            float mx = s[0] / cnt, my = s[1] / cnt, mz = s[2] / cnt;
            float n = sqrtf(mx * mx + my * my + mz * mz);
            float nn = fmaxf(n, 1e-12f);
            mx = mx / nn; my = my / nn; mz = mz / nn;
            float n2 = sqrtf(mx * mx + my * my + mz * mz);
            sMean[0] = mx; sMean[1] = my; sMean[2] = mz; sMean[3] = n2;
        }
        {
            float cnt = fmaxf(s[7], 1.f);
            float mx = s[4] / cnt, my = s[5] / cnt, mz = s[6] / cnt;
            float n = sqrtf(mx * mx + my * my + mz * mz);
            float nn = fmaxf(n, 1e-12f);
            mx = mx / nn; my = my / nn; mz = mz / nn;
            float n2 = sqrtf(mx * mx + my * my + mz * mz);
            sMean[4] = mx; sMean[5] = my; sMean[6] = mz; sMean[7] = n2;
        }
    }
    __syncthreads();
    if (t >= 64) return;

    // ---- phase B: wave-0 inlier test (round-6 logic, means from LDS) ----
    bool iL = false, iR = false;
    int x = 0;
    if (t < min(total, 64)) {
        int lo = 0, hi = 33;
        while (lo < hi) { int mid = (lo + hi) >> 1; if (sExcl[mid] <= t) lo = mid + 1; else hi = mid; }
        int w = lo - 1;
        int k = t - sExcl[w];
        u64 tmp = sUL[w] | sUR[w];
        while (k--) tmp &= tmp - 1;
        int bpos = __ffsll((unsigned long long)tmp) - 1;
        u64 bb = 1ull << bpos;
        x = w * 64 + bpos;

        float4 n = normBuf[(size_t)y * 64 + t];   // coalesced: slot == union rank == t
        float nn = sqrtf(n.x * n.x + n.y * n.y + n.z * n.z);
        float dn = fmaxf(nn, 1e-8f);
        if (sUL[w] & bb) {
            float dot = n.x * sMean[0] + n.y * sMean[1] + n.z * sMean[2];
            float c = dot / (dn * fmaxf(sMean[3], 1e-8f));
            iL = c > THRC;
        }
        if (sUR[w] & bb) {
            float dot = n.x * sMean[4] + n.y * sMean[5] + n.z * sMean[6];
            float c = dot / (dn * fmaxf(sMean[7], 1e-8f));
            iR = c > THRC;
        }
    }
    u64 balL = __ballot(iL), balR = __ballot(iR);
    u64 lm = (t == 0) ? 0ull : ((~0ull) >> (64 - t));
    if (iL) xListL[(size_t)y * 64 + __popcll(balL & lm)] = (u16)x;  // ascending x
    if (iR) xListR[(size_t)y * 64 + __popcll(balR & lm)] = (u16)x;
    if (t == 0) { cntL[y] = (int)__popcll(balL); cntR[y] = (int)__popcll(balR); }
}

// ---------------- K3: redundant scan + per-row sampling + output ------------
__device__ __forceinline__ int computePos(int i, int N) {
    if (N >= SS) {
        float t = ((float)i * (float)(N - 1)) / 1999.0f;  // float32 reference parity
        return (int)floorf(t);
    } else {
        return min(i, max(N - 1, 0));
    }
}

__global__ __launch_bounds__(256) void k_out(
        const float* __restrict__ depth, const u64* __restrict__ maskBits,
        const int* __restrict__ cntL, const int* __restrict__ cntR,
        const u16* __restrict__ xListL, const u16* __restrict__ xListR,
        float* __restrict__ out) {
#pragma clang fp contract(off)
    int y = blockIdx.x, t = threadIdx.x;
    __shared__ int sAcc[4];            // accLs, accLc, accRs, accRc
    __shared__ int sRow[6];            // cumLy, cLy, cumRy, cRy, Nl, Nr
    __shared__ float sInfo[4];         // slx, srx, sld, srd
    __shared__ int sValid;

    if (t == 0) { sAcc[0] = 0; sAcc[1] = 0; sAcc[2] = 0; sAcc[3] = 0; }

    u64 word = maskBits[(size_t)y * 32 + (t >> 3)];   // 8 threads share a word (broadcast)
    unsigned mbyte = (unsigned)((word >> ((t & 7) * 8)) & 0xFFull);
    const float4* drow = reinterpret_cast<const float4*>(depth + (size_t)y * W);
    float4 da = drow[2 * t], db = drow[2 * t + 1];
    int rowAny = __syncthreads_or(word != 0ull);      // t>>3 spans all 32 words; also fences sAcc init

    // wave 0: redundant scan of row counts -> this row's cum/cnt + totals
    if (t < 64) {
        int base = t * 24;
        int sl = 0, sr = 0;
        for (int j = 0; j < 24; ++j) { sl += cntL[base + j]; sr += cntR[base + j]; }
        int iL = sl, iR = sr;
        for (int o = 1; o < 64; o <<= 1) {
            int vl = __shfl_up(iL, o, 64), vr = __shfl_up(iR, o, 64);
            if (t >= o) { iL += vl; iR += vr; }
        }
        int Nl = __shfl(iL, 63, 64), Nr = __shfl(iR, 63, 64);
        int c = y / 24;
        int cumLy = __shfl(iL - sl, c, 64);   // exclusive base of chunk c
        int cumRy = __shfl(iR - sr, c, 64);
        if (t == 0) {
            for (int j = c * 24; j < y; ++j) { cumLy += cntL[j]; cumRy += cntR[j]; }
            sRow[0] = cumLy; sRow[1] = cntL[y];
            sRow[2] = cumRy; sRow[3] = cntR[y];
            sRow[4] = Nl;    sRow[5] = Nr;
        }
    }
    __syncthreads();
    int cumLy = sRow[0], cLy = sRow[1], cumRy = sRow[2], cRy = sRow[3];
    int Nl = sRow[4], Nr = sRow[5];
    int vc = (Nl > 0 && Nr > 0) ? 1 : 0;

    // all threads: enumerate the 2000 samples, keep those landing in this row
    if (vc && (cLy | cRy)) {
        int aS = 0, aC = 0, bS = 0, bC = 0;
        for (int i = t; i < SS; i += 256) {
            int posL = computePos(i, Nl);
            int kL = posL - cumLy;
            if (kL >= 0 && kL < cLy) { aS += (int)xListL[(size_t)y * 64 + kL]; aC++; }
            int posR = computePos(i, Nr);
            int kR = posR - cumRy;
            if (kR >= 0 && kR < cRy) { bS += (int)xListR[(size_t)y * 64 + kR]; bC++; }
        }
        // wave reduce, lane 0 adds to LDS (integer: order-free)
        for (int o = 32; o > 0; o >>= 1) {
            aS += __shfl_down(aS, o, 64); aC += __shfl_down(aC, o, 64);
            bS += __shfl_down(bS, o, 64); bC += __shfl_down(bC, o, 64);
        }
        if ((t & 63) == 0) {
            if (aC) { atomicAdd(&sAcc[0], aS); atomicAdd(&sAcc[1], aC); }
            if (bC) { atomicAdd(&sAcc[2], bS); atomicAdd(&sAcc[3], bC); }
        }
    }
    __syncthreads();

    if (t == 0) {
        int lc = sAcc[1], rc = sAcc[3];
        float lmean = (float)sAcc[0] / fmaxf((float)lc, 1.0f);
        float rmean = (float)sAcc[2] / fmaxf((float)rc, 1.0f);
        int lx = min(max((int)rintf(lmean), 0), W - 1);
        int rx = min(max((int)rintf(rmean), 0), W - 1);
        float ld = depth[(size_t)y * W + lx], rd = depth[(size_t)y * W + rx];
        int valid = (lc > 0) && (rc > 0) && vc && (!isnan(ld)) && (!isnan(rd)) && rowAny;
        sInfo[0] = (float)lx; sInfo[1] = (float)rx; sInfo[2] = ld; sInfo[3] = rd;
        sValid = valid;
    }
    __syncthreads();

    float slx = sInfo[0], srx = sInfo[1], sld = sInfo[2], srd = sInfo[3];
    int valid = sValid;
    float denom = (srx - slx) + 1e-6f;

    float d8[8] = { da.x, da.y, da.z, da.w, db.x, db.y, db.z, db.w };
    float o8[8];
    int xb = t * 8;
#pragma unroll
    for (int j = 0; j < 8; ++j) {
        float o = d8[j];
        if (valid && ((mbyte >> j) & 1u)) {
            float r = ((float)(xb + j) - slx) / denom;
            r = fminf(fmaxf(r, 0.0f), 1.0f);
            o = (1.0f - r) * sld + r * srd;
        }
        o8[j] = o;
    }
    float4* orow = reinterpret_cast<float4*>(out + (size_t)y * W);
    orow[2 * t]     = make_float4(o8[0], o8[1], o8[2], o8[3]);
    orow[2 * t + 1] = make_float4(o8[4], o8[5], o8[6], o8[7]);
}

// ---------------- launcher ---------------------------------------------------
extern "C" void kernel_launch(void* const* d_in, const int* in_sizes, int n_in,
                              void* d_out, int out_size, void* d_ws, size_t ws_size,
                              hipStream_t stream) {
    const float* depth = (const float*)d_in[0];
    const int*   mask  = (const int*)d_in[1];
    const float* Kinv  = (const float*)d_in[2];
    float* out = (float*)d_out;
    char* ws = (char*)d_ws;

    u64* bitL = (u64*)(ws + OFF_BITL);
    u64* bitR = (u64*)(ws + OFF_BITR);
    u64* maskBits = (u64*)(ws + OFF_MBITS);
    float* partials = (float*)(ws + OFF_PART);
    int* cntL = (int*)(ws + OFF_CNTL);
    int* cntR = (int*)(ws + OFF_CNTR);
    float4* normBuf = (float4*)(ws + OFF_NORM);
    u16* xListL = (u16*)(ws + OFF_XL);
    u16* xListR = (u16*)(ws + OFF_XR);

    k_row_region<<<H, 256, 0, stream>>>(depth, mask, Kinv, bitL, bitR, maskBits, normBuf, partials);
    k_mean_inlier<<<H, 256, 0, stream>>>(partials, bitL, bitR, normBuf, xListL, xListR, cntL, cntR);
    k_out<<<H, 256, 0, stream>>>(depth, maskBits, cntL, cntR, xListL, xListR, out);
}